// Round 1
// baseline (1296.528 us; speedup 1.0000x reference)
//
#include <hip/hip_runtime.h>

// Problem constants (fixed by the reference file)
constexpr int Bn = 4, Hn = 16, Sn = 2048, Dn = 64;
constexpr float MASK_FILL = -1e9f;

typedef __bf16 bf16x8 __attribute__((ext_vector_type(8)));
typedef __bf16 bf16x4 __attribute__((ext_vector_type(4)));
typedef float  f32x4  __attribute__((ext_vector_type(4)));

// LDS strides in elements (__bf16). Rows padded to keep 16B alignment
// (stride multiple of 8 elems) while breaking power-of-2 bank strides.
#define KSTRIDE 72    // K and Q/S-scratch tiles: [128][72]
#define VSTRIDE 136   // V-transposed tile:      [64][136]

// Fused attention (no softmax): per block computes a 128-row Q stripe of one
// (b,h): S = (q/8) @ k^T with mask-fill, streams S to attn out, and
// accumulates O = S @ v via bf16 MFMA.
__global__ __launch_bounds__(256, 2) void attn_fused(
    const float* __restrict__ qg, const float* __restrict__ kg,
    const float* __restrict__ vg, const int* __restrict__ maskg,
    float* __restrict__ outg, float* __restrict__ attng)
{
  __shared__ __align__(16) __bf16 lds_k [128 * KSTRIDE];
  __shared__ __align__(16) __bf16 lds_vt[ 64 * VSTRIDE];
  __shared__ __align__(16) __bf16 lds_qs[128 * KSTRIDE];  // Q tile, then per-wave S scratch
  __shared__ int lds_m[128];

  const int qt   = blockIdx.x;        // 0..15 query tile
  const int bh   = blockIdx.y;        // 0..63 (b*16+h)
  const int b    = bh >> 4;
  const int tid  = threadIdx.x;
  const int wave = tid >> 6;
  const int lane = tid & 63;
  const int quad = lane >> 4;
  const int l16  = lane & 15;

  const size_t hbase = (size_t)bh * Sn * Dn;
  const float* qp = qg + hbase + (size_t)qt * 128 * Dn;
  float* attnp = attng + (size_t)bh * Sn * Sn + (size_t)qt * 128 * (size_t)Sn;

  // ---- stage Q tile (pre-scaled by 1/temperature = 0.125, exact pow2) ----
  {
    const int r0 = tid >> 4;          // 0..15
    const int c  = (tid & 15) << 2;   // 0..60
#pragma unroll
    for (int i = 0; i < 8; ++i) {
      const int r = r0 + (i << 4);
      f32x4 val = __builtin_nontemporal_load((const f32x4*)(qp + r * Dn + c));
      bf16x4 pk;
      pk.x = (__bf16)(val.x * 0.125f);
      pk.y = (__bf16)(val.y * 0.125f);
      pk.z = (__bf16)(val.z * 0.125f);
      pk.w = (__bf16)(val.w * 0.125f);
      *(bf16x4*)&lds_qs[r * KSTRIDE + c] = pk;
    }
  }
  __syncthreads();

  // ---- hoist per-wave Q A-fragments (verified A layout: A[m=lane&15][k=quad*8+j]) ----
  bf16x8 qa[2][2];
#pragma unroll
  for (int qs = 0; qs < 2; ++qs)
#pragma unroll
    for (int ks = 0; ks < 2; ++ks)
      qa[qs][ks] = *(const bf16x8*)&lds_qs[(wave * 32 + qs * 16 + l16) * KSTRIDE + ks * 32 + quad * 8];

  // Per-wave private S scratch aliases this wave's own 32 rows of the Q tile
  // (the only rows this wave read its Q frags from — no cross-wave hazard).
  __bf16* sbuf = &lds_qs[wave * 32 * KSTRIDE];

  f32x4 oacc[2][4];
#pragma unroll
  for (int qs = 0; qs < 2; ++qs)
#pragma unroll
    for (int ds = 0; ds < 4; ++ds)
      oacc[qs][ds] = (f32x4){0.f, 0.f, 0.f, 0.f};

  for (int kt = 0; kt < 16; ++kt) {
    __syncthreads();   // previous iteration's K/V consumers are done

    // ---- stage K (row-major) and V (transposed) tiles as bf16 ----
    {
      const int r0 = tid >> 4;
      const int c  = (tid & 15) << 2;
      const float* kp = kg + hbase + (size_t)(kt * 128) * Dn;
      const float* vp = vg + hbase + (size_t)(kt * 128) * Dn;
#pragma unroll
      for (int i = 0; i < 8; ++i) {
        const int r = r0 + (i << 4);
        f32x4 kv = *(const f32x4*)(kp + r * Dn + c);
        bf16x4 pk;
        pk.x = (__bf16)kv.x; pk.y = (__bf16)kv.y;
        pk.z = (__bf16)kv.z; pk.w = (__bf16)kv.w;
        *(bf16x4*)&lds_k[r * KSTRIDE + c] = pk;
        f32x4 vv = *(const f32x4*)(vp + r * Dn + c);
        lds_vt[(c + 0) * VSTRIDE + r] = (__bf16)vv.x;
        lds_vt[(c + 1) * VSTRIDE + r] = (__bf16)vv.y;
        lds_vt[(c + 2) * VSTRIDE + r] = (__bf16)vv.z;
        lds_vt[(c + 3) * VSTRIDE + r] = (__bf16)vv.w;
      }
      if (tid < 128) lds_m[tid] = maskg[b * Sn + kt * 128 + tid];
    }
    __syncthreads();

    // ---- S = Q @ K^T  (16x16x32 bf16 MFMA; B-frag = K rows, d contiguous) ----
    f32x4 sacc[2][8];
#pragma unroll
    for (int ns = 0; ns < 8; ++ns) {
      bf16x8 kb0 = *(const bf16x8*)&lds_k[(ns * 16 + l16) * KSTRIDE +      quad * 8];
      bf16x8 kb1 = *(const bf16x8*)&lds_k[(ns * 16 + l16) * KSTRIDE + 32 + quad * 8];
#pragma unroll
      for (int qs = 0; qs < 2; ++qs) {
        f32x4 acc = (f32x4){0.f, 0.f, 0.f, 0.f};
        acc = __builtin_amdgcn_mfma_f32_16x16x32_bf16(qa[qs][0], kb0, acc, 0, 0, 0);
        acc = __builtin_amdgcn_mfma_f32_16x16x32_bf16(qa[qs][1], kb1, acc, 0, 0, 0);
        sacc[qs][ns] = acc;
      }
    }

    // ---- mask fill + stream S tile to attn (nontemporal fp32) ----
    // C/D layout (verified): col = lane&15, row = quad*4 + reg
#pragma unroll
    for (int ns = 0; ns < 8; ++ns) {
      const int col = ns * 16 + l16;
      const bool keep = (lds_m[col] != 0);
#pragma unroll
      for (int qs = 0; qs < 2; ++qs) {
#pragma unroll
        for (int rI = 0; rI < 4; ++rI) {
          float sv = keep ? sacc[qs][ns][rI] : MASK_FILL;
          sacc[qs][ns][rI] = sv;
          const int row = wave * 32 + qs * 16 + quad * 4 + rI;
          __builtin_nontemporal_store(sv, attnp + (size_t)row * Sn + kt * 128 + col);
        }
      }
    }

    // ---- O += S @ V, in two 64-col halves through per-wave LDS scratch ----
#pragma unroll
    for (int half = 0; half < 2; ++half) {
#pragma unroll
      for (int ns4 = 0; ns4 < 4; ++ns4) {
        const int ns = half * 4 + ns4;
#pragma unroll
        for (int qs = 0; qs < 2; ++qs)
#pragma unroll
          for (int rI = 0; rI < 4; ++rI)
            sbuf[(qs * 16 + quad * 4 + rI) * KSTRIDE + ns4 * 16 + l16] = (__bf16)sacc[qs][ns][rI];
      }
      // Same-wave DS ops execute in order; fence only stops compiler reordering.
      asm volatile("" ::: "memory");
#pragma unroll
      for (int ks = 0; ks < 2; ++ks) {
        bf16x8 sa0 = *(const bf16x8*)&sbuf[(     l16) * KSTRIDE + ks * 32 + quad * 8];
        bf16x8 sa1 = *(const bf16x8*)&sbuf[(16 + l16) * KSTRIDE + ks * 32 + quad * 8];
#pragma unroll
        for (int ds = 0; ds < 4; ++ds) {
          bf16x8 vb = *(const bf16x8*)&lds_vt[(ds * 16 + l16) * VSTRIDE + half * 64 + ks * 32 + quad * 8];
          oacc[0][ds] = __builtin_amdgcn_mfma_f32_16x16x32_bf16(sa0, vb, oacc[0][ds], 0, 0, 0);
          oacc[1][ds] = __builtin_amdgcn_mfma_f32_16x16x32_bf16(sa1, vb, oacc[1][ds], 0, 0, 0);
        }
      }
      asm volatile("" ::: "memory");  // keep next half's sbuf writes after these reads
    }
  }

  // ---- epilogue: write O (fp32, nontemporal) ----
  float* op = outg + hbase + (size_t)qt * 128 * Dn;
#pragma unroll
  for (int qs = 0; qs < 2; ++qs)
#pragma unroll
    for (int ds = 0; ds < 4; ++ds)
#pragma unroll
      for (int rI = 0; rI < 4; ++rI) {
        const int row = wave * 32 + qs * 16 + quad * 4 + rI;
        __builtin_nontemporal_store(oacc[qs][ds][rI], op + (size_t)row * Dn + ds * 16 + l16);
      }
}

extern "C" void kernel_launch(void* const* d_in, const int* in_sizes, int n_in,
                              void* d_out, int out_size, void* d_ws, size_t ws_size,
                              hipStream_t stream) {
  const float* q    = (const float*)d_in[0];
  const float* k    = (const float*)d_in[1];
  const float* v    = (const float*)d_in[2];
  const int*   mask = (const int*)d_in[3];
  float* out  = (float*)d_out;
  float* attn = out + (size_t)Bn * Hn * Sn * Dn;   // outputs concatenated: (output, attn)

  dim3 grid(Sn / 128, Bn * Hn);
  attn_fused<<<grid, 256, 0, stream>>>(q, k, v, mask, out, attn);
}